// Round 8
// baseline (900.259 us; speedup 1.0000x reference)
//
#include <hip/hip_runtime.h>

#define NROWS  65536
#define CDIM   128
#define MKEYS  1024
#define WROWS  32     // q-rows per 1-wave block

typedef _Float16 half8 __attribute__((ext_vector_type(8)));
typedef _Float16 half4 __attribute__((ext_vector_type(4)));
typedef float    floatx4 __attribute__((ext_vector_type(4)));

union FU { float f; unsigned u; };

#define MFMA16 __builtin_amdgcn_mfma_f32_16x16x32_f16

// ---------------- Kernel A: convert keys fp32 -> fp16 in MFMA-fragment order --------
// Layout: for key k, dim d:  g=k>>4, n=k&15, f=d>>5, q8=(d&31)>>3, e=d&7
//   kh[ ((g*4+f)*64 + q8*16 + n)*8 + e ]  = (fp16) keys[k][d]
// Fragment (g,f) load: kh + (g*4+f)*512 + lane*8 -> 64 lanes x 16B contiguous.
__global__ __launch_bounds__(256) void cvt_keys_kernel(const float* __restrict__ keys,
                                                       _Float16* __restrict__ kh) {
    int i  = blockIdx.x * 256 + threadIdx.x;        // 32768 threads
    int k  = i >> 5;                                // key 0..1023
    int d0 = (i & 31) * 4;                          // dim 0,4,...,124
    float4 f4 = *(const float4*)(keys + (long)k * CDIM + d0);
    half4 hv;
    hv[0] = (_Float16)f4.x; hv[1] = (_Float16)f4.y;
    hv[2] = (_Float16)f4.z; hv[3] = (_Float16)f4.w;
    int g = k >> 4, n = k & 15;
    int f = d0 >> 5, q8 = (d0 & 31) >> 3, e = d0 & 7;
    long idx = ((long)((g * 4 + f) * 64 + q8 * 16 + n)) * 8 + e;
    *(half4*)(kh + idx) = hv;
}

// ---------------- Kernel B: 1-WAVE blocks, 32 rows/wave, 2048 blocks ----------------
// Residency experiment: no multi-wave barriers, <1KB LDS, VGPR<128 -> a CU always
// holds 8 of these waves; the whole grid is co-resident. All coordination in-wave.
// Math identical to the correctness-proven R6: same MFMA fragment layouts, same
// branch-free top-2, same threshold thr = M1 - 2*e1 - slack, same rigor chain
// (sole candidate -> winner directly; multi-candidate -> exact fp32 rescore;
// quad-top-2 >= thr -> exact full rescan of that row).
__global__ __launch_bounds__(64) void gather_main(
    const float* __restrict__ q,      // trend_representation (65536x128)
    const float* __restrict__ rep,    // representation
    const float* __restrict__ keys,   // fp32 keys (1024x128)
    const float* __restrict__ vals,   // fp32 values
    const _Float16* __restrict__ kh,  // fp16 keys, fragment order (ws)
    float* __restrict__ out)          // [131072]: keys_g then values_g
{
    __shared__ unsigned long long rowBest[WROWS];   // 256 B
    __shared__ int candKey[WROWS][4];               // 512 B
    __shared__ int candCnt[WROWS];
    __shared__ int rowNeed[WROWS];                  // 0 none / 1 rescore / 2 rescan
    __shared__ int rowIdx[WROWS];

    const int lane = threadIdx.x;     // 0..63
    const int n    = lane & 15;       // A: key-in-16; B/C: q-row (col) in 16
    const int quad = lane >> 4;       // k-slice selector / C row group
    const long g0  = (long)blockIdx.x * WROWS;

    if (lane < WROWS) { rowBest[lane] = 0ull; candCnt[lane] = 0; rowNeed[lane] = 0; }

    // ---- P1: q fragments for rows n and 16+n direct from global; row sumsq ----
    // B-frag f covers dims f*32 + quad*8 .. +8 of its row (same as R6's LDS read).
    half8 qa0, qa1, qa2, qa3, qb0, qb1, qb2, qb3;
    float ssA = 0.f, ssB = 0.f;
    {
        const float* ra = q + (g0 + n)      * CDIM + quad * 8;
        const float* rb = q + (g0 + 16 + n) * CDIM + quad * 8;
#define LOADQ(dst, base, f, ss) {                                        \
        float4 x = *(const float4*)((base) + (f) * 32);                  \
        float4 y = *(const float4*)((base) + (f) * 32 + 4);              \
        ss += x.x*x.x + x.y*x.y + x.z*x.z + x.w*x.w                      \
            + y.x*y.x + y.y*y.y + y.z*y.z + y.w*y.w;                     \
        half8 hv;                                                        \
        hv[0]=(_Float16)x.x; hv[1]=(_Float16)x.y;                        \
        hv[2]=(_Float16)x.z; hv[3]=(_Float16)x.w;                        \
        hv[4]=(_Float16)y.x; hv[5]=(_Float16)y.y;                        \
        hv[6]=(_Float16)y.z; hv[7]=(_Float16)y.w;                        \
        dst = hv; }
        LOADQ(qa0, ra, 0, ssA); LOADQ(qa1, ra, 1, ssA);
        LOADQ(qa2, ra, 2, ssA); LOADQ(qa3, ra, 3, ssA);
        LOADQ(qb0, rb, 0, ssB); LOADQ(qb1, rb, 1, ssB);
        LOADQ(qb2, rb, 2, ssB); LOADQ(qb3, rb, 3, ssB);
        // full row norms: sum the 4 quads' partial sums
        ssA += __shfl_xor(ssA, 16); ssA += __shfl_xor(ssA, 32);
        ssB += __shfl_xor(ssB, 16); ssB += __shfl_xor(ssB, 32);
    }

    // ---- P2: K-loop, 64 chunks x 16 keys; 8 MFMA (2 chains) + branch-free top-2 ----
    float b1a = -3.4e38f, b2a = -3.4e38f; int i1a = 0;
    float b1b = -3.4e38f, b2b = -3.4e38f; int i1b = 0;
    const _Float16* kb = kh + lane * 8;

#define TOP2(s_, b1_, b2_, i1_, keyb_) {                                      \
        float s0 = s_[0], s1 = s_[1], s2 = s_[2], s3 = s_[3];                 \
        float m01 = fmaxf(s0, s1), m23 = fmaxf(s2, s3);                       \
        int   j01 = (s1 > s0) ? 1 : 0, j23 = (s3 > s2) ? 3 : 2;               \
        float c1 = fmaxf(m01, m23);                                           \
        int   jc = (m23 > m01) ? j23 : j01;                                   \
        float c2 = fmaxf(fminf(m01, m23), fmaxf(fminf(s0, s1), fminf(s2, s3)));\
        bool better = c1 > b1_;                                               \
        b2_ = fmaxf(fminf(b1_, c1), fmaxf(b2_, c2));                          \
        b1_ = fmaxf(b1_, c1);                                                 \
        i1_ = better ? ((keyb_) + jc) : i1_; }

    for (int ch = 0; ch < 64; ++ch) {
        const _Float16* kp = kb + (long)ch * 2048;   // (ch*4+f)*512 + lane*8
        half8 a0 = *(const half8*)(kp);
        half8 a1 = *(const half8*)(kp + 512);
        half8 a2 = *(const half8*)(kp + 1024);
        half8 a3 = *(const half8*)(kp + 1536);
        floatx4 accA = {0.f, 0.f, 0.f, 0.f};
        floatx4 accB = {0.f, 0.f, 0.f, 0.f};
        accA = MFMA16(a0, qa0, accA, 0, 0, 0);
        accB = MFMA16(a0, qb0, accB, 0, 0, 0);
        accA = MFMA16(a1, qa1, accA, 0, 0, 0);
        accB = MFMA16(a1, qb1, accB, 0, 0, 0);
        accA = MFMA16(a2, qa2, accA, 0, 0, 0);
        accB = MFMA16(a2, qb2, accB, 0, 0, 0);
        accA = MFMA16(a3, qa3, accA, 0, 0, 0);
        accB = MFMA16(a3, qb3, accB, 0, 0, 0);
        int keyb = ch * 16 + quad * 4;               // C: m = quad*4 + reg
        TOP2(accA, b1a, b2a, i1a, keyb);
        TOP2(accB, b1b, b2b, i1b, keyb);
    }

    // ---- P3: merge top-1 across quads (disjoint keys, same row) ----
#define QMERGE(m_, j_) {                                                   \
        float om; int oi;                                                  \
        om = __shfl_xor(m_, 16); oi = __shfl_xor(j_, 16);                  \
        if (om > m_ || (om == m_ && oi < j_)) { m_ = om; j_ = oi; }        \
        om = __shfl_xor(m_, 32); oi = __shfl_xor(j_, 32);                  \
        if (om > m_ || (om == m_ && oi < j_)) { m_ = om; j_ = oi; } }
    float mA = b1a; int jA = i1a; float mB = b1b; int jB = i1b;
    QMERGE(mA, jA); QMERGE(mB, jB);

    // ---- P4: thresholds + candidate voting (per-quad top-1s; LDS scalars) ----
    float thrA = mA - 2.f * (0.0168f * sqrtf(ssA) + 0.002f) - 0.02f;
    float thrB = mB - 2.f * (0.0168f * sqrtf(ssB) + 0.002f) - 0.02f;
    {
        if (b1a >= thrA) { int p = atomicAdd(&candCnt[n], 1);      candKey[n][p & 3] = i1a; }
        if (b2a >= thrA) atomicOr(&rowNeed[n], 2);
        if (b1b >= thrB) { int p = atomicAdd(&candCnt[16 + n], 1); candKey[16 + n][p & 3] = i1b; }
        if (b2b >= thrB) atomicOr(&rowNeed[16 + n], 2);
    }
    __syncthreads();
    if (lane < WROWS) {
        int cnt = candCnt[lane], need = rowNeed[lane];
        if (need == 0 && cnt > 1) { need = 1; rowNeed[lane] = 1; }
        if (need == 0) rowIdx[lane] = candKey[lane][0];   // sole cand == exact argmax
    }
    __syncthreads();

    // ---- P5: exact fp32 rescore of candidates (rare rows; 4 slots in parallel) ----
#define ENCMAX(v_, key_, dst_) {                                           \
        FU su; su.f = (v_);                                                \
        unsigned ord = (su.u & 0x80000000u) ? ~su.u : (su.u | 0x80000000u);\
        unsigned long long enc = ((unsigned long long)ord << 32)           \
                               | (unsigned)(1023 - (key_));                \
        atomicMax(&rowBest[dst_], enc); }
    for (int r = 0; r < WROWS; ++r) {
        if (rowNeed[r] == 1) {
            int cnt = candCnt[r];
            if (quad < cnt) {
                int key = candKey[r][quad];
                const float* qp  = q + (g0 + r) * CDIM + n * 8;
                const float* kp2 = keys + (long)key * CDIM + n * 8;
                float4 xa = *(const float4*)(qp),      xb = *(const float4*)(qp + 4);
                float4 ya = *(const float4*)(kp2),     yb = *(const float4*)(kp2 + 4);
                float v = xa.x*ya.x + xa.y*ya.y + xa.z*ya.z + xa.w*ya.w
                        + xb.x*yb.x + xb.y*yb.y + xb.z*yb.z + xb.w*yb.w;
                v += __shfl_xor(v, 1); v += __shfl_xor(v, 2);
                v += __shfl_xor(v, 4); v += __shfl_xor(v, 8);
                if (n == 0) ENCMAX(v, key, r);
            }
        }
    }
    // ---- P6: overflow rows -> exact full rescan (rigor path, ~1%/row) ----
    for (int r = 0; r < WROWS; ++r) {
        if (rowNeed[r] == 2) {
            const float* qp = q + (g0 + r) * CDIM + n * 8;
            float4 xa = *(const float4*)(qp), xb = *(const float4*)(qp + 4);
            for (int it = 0; it < 256; ++it) {
                int key = it * 4 + quad;
                const float* kp2 = keys + (long)key * CDIM + n * 8;
                float4 ya = *(const float4*)(kp2), yb = *(const float4*)(kp2 + 4);
                float v = xa.x*ya.x + xa.y*ya.y + xa.z*ya.z + xa.w*ya.w
                        + xb.x*yb.x + xb.y*yb.y + xb.z*yb.z + xb.w*yb.w;
                v += __shfl_xor(v, 1); v += __shfl_xor(v, 2);
                v += __shfl_xor(v, 4); v += __shfl_xor(v, 8);
                if (n == 0) ENCMAX(v, key, r);
            }
        }
    }
    __syncthreads();
    if (lane < WROWS && rowNeed[lane]) {
        unsigned long long b = rowBest[lane];
        rowIdx[lane] = 1023 - (int)(unsigned)(b & 0xffffffffull);
    }
    __syncthreads();

    // ---- P7: gather: 2 lanes per row, 64 dims each ----
    {
        int row = lane >> 1, half = lane & 1;
        int idx = rowIdx[row];
        long g = g0 + row;
        const float4* qp  = (const float4*)(q    + g * CDIM + half * 64);
        const float4* kp2 = (const float4*)(keys + (long)idx * CDIM + half * 64);
        const float4* rp  = (const float4*)(rep  + g * CDIM + half * 64);
        const float4* vp  = (const float4*)(vals + (long)idx * CDIM + half * 64);
        float kg = 0.f, vg = 0.f;
        #pragma unroll
        for (int h = 0; h < 16; ++h) {
            float4 qa = qp[h], ka = kp2[h], ra = rp[h], va = vp[h];
            float d0 = qa.x - ka.x, d1 = qa.y - ka.y, d2 = qa.z - ka.z, d3 = qa.w - ka.w;
            kg += d0*d0 + d1*d1 + d2*d2 + d3*d3;
            float e0 = ra.x - va.x, e1 = ra.y - va.y, e2 = ra.z - va.z, e3 = ra.w - va.w;
            vg += e0*e0 + e1*e1 + e2*e2 + e3*e3;
        }
        kg += __shfl_xor(kg, 1);
        vg += __shfl_xor(vg, 1);
        if (half == 0) { out[g] = kg; out[NROWS + g] = vg; }
    }
}

extern "C" void kernel_launch(void* const* d_in, const int* in_sizes, int n_in,
                              void* d_out, int out_size, void* d_ws, size_t ws_size,
                              hipStream_t stream) {
    const float* q    = (const float*)d_in[0];  // trend_representation
    const float* rep  = (const float*)d_in[1];  // representation
    const float* keys = (const float*)d_in[2];
    const float* vals = (const float*)d_in[3];
    _Float16* kh = (_Float16*)d_ws;             // 256 KB fp16 key cache (fragment order)

    cvt_keys_kernel<<<128, 256, 0, stream>>>(keys, kh);
    gather_main<<<NROWS / WROWS, 64, 0, stream>>>(q, rep, keys, vals, kh,
                                                  (float*)d_out);
}

// Round 9
// 188.369 us; speedup vs baseline: 4.7792x; 4.7792x over previous
//
#include <hip/hip_runtime.h>

#define NROWS  65536
#define CDIM   128
#define MKEYS  1024
#define BROWS  256    // rows per block
#define TROWS  16     // rows per tile
#define NTILES 16
#define CANDCAP 32

typedef _Float16 half8 __attribute__((ext_vector_type(8)));
typedef _Float16 half4 __attribute__((ext_vector_type(4)));
typedef float    floatx4 __attribute__((ext_vector_type(4)));

union FU { float f; unsigned u; };

#define MFMA16 __builtin_amdgcn_mfma_f32_16x16x32_f16

// ---------------- Kernel A: convert keys fp32 -> fp16 in MFMA-fragment order --------
// Layout: for key k, dim d:  g=k>>4, n=k&15, f=d>>5, q8=(d&31)>>3, e=d&7
//   kh[ ((g*4+f)*64 + q8*16 + n)*8 + e ] = (fp16) keys[k][d]
// Fragment (g,f): kh + (g*4+f)*512 + lane*8  -> 64 lanes x 16B contiguous.
__global__ __launch_bounds__(256) void cvt_keys_kernel(const float* __restrict__ keys,
                                                       _Float16* __restrict__ kh) {
    int i  = blockIdx.x * 256 + threadIdx.x;        // 32768 threads
    int k  = i >> 5;                                // key 0..1023
    int d0 = (i & 31) * 4;                          // dim 0,4,...,124
    float4 f4 = *(const float4*)(keys + (long)k * CDIM + d0);
    half4 hv;
    hv[0] = (_Float16)f4.x; hv[1] = (_Float16)f4.y;
    hv[2] = (_Float16)f4.z; hv[3] = (_Float16)f4.w;
    int g = k >> 4, n = k & 15;
    int f = d0 >> 5, q8 = (d0 & 31) >> 3, e = d0 & 7;
    long idx = ((long)((g * 4 + f) * 64 + q8 * 16 + n)) * 8 + e;
    *(half4*)(kh + idx) = hv;
}

// ---------------- Kernel B: keys-in-registers persistent block -----------------------
// 256 blocks (1/CU) x 8 waves. Each wave holds 128 keys (32 half8 = 128 VGPR) loaded
// ONCE. Per 16-row q-tile: pass1 register-MFMA -> per-row max M1 -> thr = M1-2e1-slack;
// pass2 bit-identical recompute pushes ALL keys >= thr (complete candidate list).
// cnt==1 -> exact argmax directly; cnt>=2 -> exact fp32 rescore (lowest-key ties);
// cnt>CANDCAP -> exact full rescan. Gather batched at block end.
__global__ __launch_bounds__(512, 2) void gather_main(
    const float* __restrict__ q,      // trend_representation (65536x128)
    const float* __restrict__ rep,    // representation
    const float* __restrict__ keys,   // fp32 keys (1024x128)
    const float* __restrict__ vals,   // fp32 values
    const _Float16* __restrict__ kh,  // fp16 keys, fragment order (ws)
    float* __restrict__ out)          // [131072]: keys_g then values_g
{
    __shared__ _Float16 qh[TROWS][128];            // 4 KB, swizzled fp16 q-tile
    __shared__ float qss[TROWS][17];               // per-(row,c8) sumsq
    __shared__ float wtv[8][TROWS];                // per-wave per-row max
    __shared__ float rowT[TROWS];
    __shared__ int   candCnt[TROWS];
    __shared__ int   candKey[TROWS][CANDCAP];
    __shared__ int   rowNeed[TROWS];
    __shared__ int   rowOvf[TROWS];
    __shared__ unsigned long long rowBest[TROWS];
    __shared__ int   rowIdxAll[BROWS];             // 1 KB

    const int t    = threadIdx.x;     // 0..511
    const int w    = t >> 6;          // wave 0..7 (owns keys w*128..w*128+127)
    const int lane = t & 63;
    const int n    = lane & 15;       // q-row (C col) in tile
    const int quad = lane >> 4;       // key sub-slice / C row group
    const long blk0 = (long)blockIdx.x * BROWS;

    // ---- preload this wave's 128 keys into 32 half8 registers (one burst) ----
    const _Float16* kb = kh + (long)w * 16384 + lane * 8;
#define KD(g) k##g##0, k##g##1, k##g##2, k##g##3
    half8 KD(0), KD(1), KD(2), KD(3), KD(4), KD(5), KD(6), KD(7);
#define KL(g) \
    k##g##0 = *(const half8*)(kb + ((g)*4 + 0) * 512); \
    k##g##1 = *(const half8*)(kb + ((g)*4 + 1) * 512); \
    k##g##2 = *(const half8*)(kb + ((g)*4 + 2) * 512); \
    k##g##3 = *(const half8*)(kb + ((g)*4 + 3) * 512);
    KL(0) KL(1) KL(2) KL(3) KL(4) KL(5) KL(6) KL(7)

#define ENCMAX(v_, key_, dst_) {                                           \
        FU su; su.f = (v_);                                                \
        unsigned ord = (su.u & 0x80000000u) ? ~su.u : (su.u | 0x80000000u);\
        unsigned long long enc = ((unsigned long long)ord << 32)           \
                               | (unsigned)(1023 - (key_));                \
        atomicMax(&rowBest[dst_], enc); }

    for (int tile = 0; tile < NTILES; ++tile) {
        const long g0 = blk0 + tile * TROWS;

        // ---- stage q-tile (waves 0-3) + reset row state (wave 4) ----
        if (t < 256) {
            int row = t >> 4, c8 = t & 15;
            const float4* src = (const float4*)(q + (g0 + row) * CDIM + c8 * 8);
            float4 a0 = src[0], a1 = src[1];
            qss[row][c8] = a0.x*a0.x + a0.y*a0.y + a0.z*a0.z + a0.w*a0.w
                         + a1.x*a1.x + a1.y*a1.y + a1.z*a1.z + a1.w*a1.w;
            half8 hv;
            hv[0] = (_Float16)a0.x; hv[1] = (_Float16)a0.y;
            hv[2] = (_Float16)a0.z; hv[3] = (_Float16)a0.w;
            hv[4] = (_Float16)a1.x; hv[5] = (_Float16)a1.y;
            hv[6] = (_Float16)a1.z; hv[7] = (_Float16)a1.w;
            int phys = c8 ^ (row & 7);
            *(half8*)&qh[row][phys * 8] = hv;
        } else if (t < 256 + TROWS) {
            int r = t - 256;
            candCnt[r] = 0; rowOvf[r] = 0; rowBest[r] = 0ull;
        }
        __syncthreads();

        // ---- B-fragments for row n (shared by both passes) ----
        int x = n & 7;
        half8 qf0 = *(const half8*)&qh[n][((0 * 4 + quad) ^ x) * 8];
        half8 qf1 = *(const half8*)&qh[n][((1 * 4 + quad) ^ x) * 8];
        half8 qf2 = *(const half8*)&qh[n][((2 * 4 + quad) ^ x) * 8];
        half8 qf3 = *(const half8*)&qh[n][((3 * 4 + quad) ^ x) * 8];

        // ---- pass 1: per-lane max over this wave's keys (value only) ----
        float m1 = -3.4e38f;
#define P1(g) { floatx4 acc = {0.f,0.f,0.f,0.f};                         \
        acc = MFMA16(k##g##0, qf0, acc, 0, 0, 0);                        \
        acc = MFMA16(k##g##1, qf1, acc, 0, 0, 0);                        \
        acc = MFMA16(k##g##2, qf2, acc, 0, 0, 0);                        \
        acc = MFMA16(k##g##3, qf3, acc, 0, 0, 0);                        \
        m1 = fmaxf(m1, fmaxf(fmaxf(acc[0], acc[1]), fmaxf(acc[2], acc[3]))); }
        P1(0) P1(1) P1(2) P1(3) P1(4) P1(5) P1(6) P1(7)
        // merge across quads (same row, disjoint keys)
        m1 = fmaxf(m1, __shfl_xor(m1, 16));
        m1 = fmaxf(m1, __shfl_xor(m1, 32));
        if (lane < TROWS) wtv[w][n] = m1;
        __syncthreads();

        // ---- threshold per row: thr = M1 - 2*e1 - slack ----
        if (t < TROWS) {
            float M1 = wtv[0][t];
            #pragma unroll
            for (int ww = 1; ww < 8; ++ww) M1 = fmaxf(M1, wtv[ww][t]);
            float qn2 = 0.f;
            #pragma unroll
            for (int j = 0; j < 16; ++j) qn2 += qss[t][j];
            // fp16 rounding: |s~ - s| <= 2^-10*1.01*||q||*||k||max(<=17) + slack
            float e1 = 0.0168f * sqrtf(qn2) + 0.002f;
            rowT[t] = M1 - 2.f * e1 - 0.02f;
        }
        __syncthreads();

        // ---- pass 2: bit-identical recompute; push ALL keys >= thr ----
        float thr = rowT[n];
#define PUSHK(K_) { int p = atomicAdd(&candCnt[n], 1);                   \
        if (p < CANDCAP) candKey[n][p] = (K_); else rowOvf[n] = 1; }
#define P2(g) { floatx4 acc = {0.f,0.f,0.f,0.f};                         \
        acc = MFMA16(k##g##0, qf0, acc, 0, 0, 0);                        \
        acc = MFMA16(k##g##1, qf1, acc, 0, 0, 0);                        \
        acc = MFMA16(k##g##2, qf2, acc, 0, 0, 0);                        \
        acc = MFMA16(k##g##3, qf3, acc, 0, 0, 0);                        \
        int keyb = ((w * 8 + (g)) << 4) + (quad << 2);                   \
        if (acc[0] >= thr) PUSHK(keyb);                                  \
        if (acc[1] >= thr) PUSHK(keyb + 1);                              \
        if (acc[2] >= thr) PUSHK(keyb + 2);                              \
        if (acc[3] >= thr) PUSHK(keyb + 3); }
        P2(0) P2(1) P2(2) P2(3) P2(4) P2(5) P2(6) P2(7)
        __syncthreads();

        // ---- resolve: sole candidate == exact argmax; else exact rescore ----
        if (t < TROWS) {
            int cnt = candCnt[t];
            if (!rowOvf[t] && cnt == 1) {
                rowIdxAll[tile * TROWS + t] = candKey[t][0];
                rowNeed[t] = 0;
            } else {
                rowNeed[t] = 1;
            }
        }
        __syncthreads();

        // ---- exact fp32 rescore: 32 groups of 16 lanes; coalesced 512B dots ----
        {
            int grp = t >> 4, l16 = t & 15;
            #pragma unroll 1
            for (int sweep = 0; sweep < 16; ++sweep) {
                int item = sweep * 32 + grp;       // (row, slot) = (item>>5, item&31)
                int row = item >> 5, slot = item & 31;
                if (rowNeed[row] && !rowOvf[row] && slot < candCnt[row]) {
                    int key = candKey[row][slot];
                    const float* qp  = q + (g0 + row) * CDIM + l16 * 8;
                    const float* kp2 = keys + (long)key * CDIM + l16 * 8;
                    float4 xa = *(const float4*)(qp),  xb = *(const float4*)(qp + 4);
                    float4 ya = *(const float4*)(kp2), yb = *(const float4*)(kp2 + 4);
                    float v = xa.x*ya.x + xa.y*ya.y + xa.z*ya.z + xa.w*ya.w
                            + xb.x*yb.x + xb.y*yb.y + xb.z*yb.z + xb.w*yb.w;
                    v += __shfl_xor(v, 1); v += __shfl_xor(v, 2);
                    v += __shfl_xor(v, 4); v += __shfl_xor(v, 8);
                    if (l16 == 0) ENCMAX(v, key, row);
                }
            }
            // overflow fallback: exact full rescan (rigor path, ~never)
            for (int rr = 0; rr < TROWS; ++rr) {
                if (rowOvf[rr]) {
                    const float* qp = q + (g0 + rr) * CDIM + l16 * 8;
                    float4 xa = *(const float4*)(qp), xb = *(const float4*)(qp + 4);
                    for (int it = 0; it < 32; ++it) {
                        int key = it * 32 + grp;
                        const float* kp2 = keys + (long)key * CDIM + l16 * 8;
                        float4 ya = *(const float4*)(kp2), yb = *(const float4*)(kp2 + 4);
                        float v = xa.x*ya.x + xa.y*ya.y + xa.z*ya.z + xa.w*ya.w
                                + xb.x*yb.x + xb.y*yb.y + xb.z*yb.z + xb.w*yb.w;
                        v += __shfl_xor(v, 1); v += __shfl_xor(v, 2);
                        v += __shfl_xor(v, 4); v += __shfl_xor(v, 8);
                        if (l16 == 0) ENCMAX(v, key, rr);
                    }
                }
            }
        }
        __syncthreads();
        if (t < TROWS && rowNeed[t]) {
            rowIdxAll[tile * TROWS + t] =
                1023 - (int)(unsigned)(rowBest[t] & 0xffffffffull);
        }
        __syncthreads();
    }

    // ---- batched gather: 8 passes x 32 rows, 16 lanes per row ----
    {
        int l16 = t & 15;
        #pragma unroll 1
        for (int pass = 0; pass < 8; ++pass) {
            int row = pass * 32 + (t >> 4);
            int idx = rowIdxAll[row];
            long g = blk0 + row;
            const float* qp  = q    + g * CDIM + l16 * 8;
            const float* kp2 = keys + (long)idx * CDIM + l16 * 8;
            const float* rp  = rep  + g * CDIM + l16 * 8;
            const float* vp  = vals + (long)idx * CDIM + l16 * 8;
            float4 qa = *(const float4*)(qp),  qb = *(const float4*)(qp + 4);
            float4 ka = *(const float4*)(kp2), kb4 = *(const float4*)(kp2 + 4);
            float4 ra = *(const float4*)(rp),  rb = *(const float4*)(rp + 4);
            float4 va = *(const float4*)(vp),  vb = *(const float4*)(vp + 4);
            float d0 = qa.x-ka.x, d1 = qa.y-ka.y, d2 = qa.z-ka.z, d3 = qa.w-ka.w;
            float d4 = qb.x-kb4.x, d5 = qb.y-kb4.y, d6 = qb.z-kb4.z, d7 = qb.w-kb4.w;
            float kg = d0*d0+d1*d1+d2*d2+d3*d3+d4*d4+d5*d5+d6*d6+d7*d7;
            float e0 = ra.x-va.x, e1 = ra.y-va.y, e2 = ra.z-va.z, e3 = ra.w-va.w;
            float e4 = rb.x-vb.x, e5 = rb.y-vb.y, e6 = rb.z-vb.z, e7 = rb.w-vb.w;
            float vg = e0*e0+e1*e1+e2*e2+e3*e3+e4*e4+e5*e5+e6*e6+e7*e7;
            kg += __shfl_xor(kg, 1); kg += __shfl_xor(kg, 2);
            kg += __shfl_xor(kg, 4); kg += __shfl_xor(kg, 8);
            vg += __shfl_xor(vg, 1); vg += __shfl_xor(vg, 2);
            vg += __shfl_xor(vg, 4); vg += __shfl_xor(vg, 8);
            if (l16 == 0) { out[g] = kg; out[NROWS + g] = vg; }
        }
    }
}

extern "C" void kernel_launch(void* const* d_in, const int* in_sizes, int n_in,
                              void* d_out, int out_size, void* d_ws, size_t ws_size,
                              hipStream_t stream) {
    const float* q    = (const float*)d_in[0];  // trend_representation
    const float* rep  = (const float*)d_in[1];  // representation
    const float* keys = (const float*)d_in[2];
    const float* vals = (const float*)d_in[3];
    _Float16* kh = (_Float16*)d_ws;             // 256 KB fp16 key cache (fragment order)

    cvt_keys_kernel<<<128, 256, 0, stream>>>(keys, kh);
    gather_main<<<NROWS / BROWS, 512, 0, stream>>>(q, rep, keys, vals, kh,
                                                   (float*)d_out);
}